// Round 4
// baseline (326.940 us; speedup 1.0000x reference)
//
#include <hip/hip_runtime.h>
#include <hip/hip_bf16.h>

#define KREAL 4369
#define KP    4416   // 69 * 64
#define NT    69     // K-tiles of 64
#define NDIM  4096
#define MROWS 8192

typedef unsigned short u16;
typedef __attribute__((ext_vector_type(8))) __bf16 bf16x8;
typedef __attribute__((ext_vector_type(8))) u16 u16x8;
typedef __attribute__((ext_vector_type(4))) float f32x4;
typedef __attribute__((ext_vector_type(16))) float f32x16;

__device__ __forceinline__ u16 bf16rne(float f) {
  unsigned int u = __builtin_bit_cast(unsigned int, f);
  u += 0x7fffu + ((u >> 16) & 1u);
  return (u16)(u >> 16);
}

// ---------------- feature kernel: xb[row][t] = bf16(polyfeat(z_row)[t]) ----------------
__global__ void feat_kernel(const float* __restrict__ z, u16* __restrict__ xb) {
  __shared__ float zs[16];
  const int row = blockIdx.x;
  const int tid = threadIdx.x;
  if (tid < 16) zs[tid] = z[row * 16 + tid];
  __syncthreads();
  u16* xrow = xb + (size_t)row * KP;
  for (int g = tid; g < KP / 8; g += 256) {
    u16x8 pack;
#pragma unroll
    for (int e = 0; e < 8; ++e) {
      int t = g * 8 + e;
      float v;
      if (t >= KREAL) v = 0.0f;
      else if (t == 0) v = 1.0f;
      else if (t < 17) v = zs[t - 1];
      else if (t < 273) { int u = t - 17; v = zs[u >> 4] * zs[u & 15]; }
      else { int u = t - 273; v = zs[(u >> 8) & 15] * (zs[(u >> 4) & 15] * zs[u & 15]); }
      pack[e] = bf16rne(v);
    }
    *reinterpret_cast<u16x8*>(xrow + g * 8) = pack;
  }
}

// ------- W convert+transpose: wbt[d][t] = bf16(W[t][d] + (t==0 ? b[d] : 0)), t>=KREAL -> 0 -------
__global__ void wconv_kernel(const float* __restrict__ W, const float* __restrict__ bias,
                             u16* __restrict__ wbt) {
  __shared__ float tile[64][68];
  const int t0 = blockIdx.x * 64;
  const int d0 = blockIdx.y * 64;
  const int tid = threadIdx.x;
  const int d4 = (tid & 15) * 4;   // float4 column within tile
  const int rb = tid >> 4;         // 0..15
#pragma unroll
  for (int p = 0; p < 4; ++p) {
    const int r = p * 16 + rb;
    const int t = t0 + r;
    f32x4 v = {0.f, 0.f, 0.f, 0.f};
    if (t < KREAL) {
      v = *reinterpret_cast<const f32x4*>(W + (size_t)t * NDIM + d0 + d4);
      if (t == 0) {
        f32x4 bb = *reinterpret_cast<const f32x4*>(bias + d0 + d4);
        v.x += bb.x; v.y += bb.y; v.z += bb.z; v.w += bb.w;
      }
    }
#pragma unroll
    for (int j = 0; j < 4; ++j) tile[r][d4 + j] = v[j];
  }
  __syncthreads();
#pragma unroll
  for (int round = 0; round < 2; ++round) {
    const int v = round * 256 + tid;
    const int d = v >> 3;   // 0..63
    const int tg = v & 7;   // 0..7
    u16x8 pack;
#pragma unroll
    for (int e = 0; e < 8; ++e) pack[e] = bf16rne(tile[tg * 8 + e][d]);
    *reinterpret_cast<u16x8*>(wbt + (size_t)(d0 + d) * KP + t0 + tg * 8) = pack;
  }
}

// ---------------- 256x256 8-phase GEMM (32x32x16 MFMA): out = xb @ wbt^T ----------------
#define GLOAD(gp, lp)                                                                     \
  __builtin_amdgcn_global_load_lds((const __attribute__((address_space(1))) unsigned int*)(gp), \
                                   (__attribute__((address_space(3))) unsigned int*)(lp), 16, 0, 0)

__device__ __forceinline__ void bar() {
  asm volatile("" ::: "memory");
  __builtin_amdgcn_s_barrier();
  asm volatile("" ::: "memory");
}

__global__ __launch_bounds__(512, 2) void gemm_kernel(const u16* __restrict__ xb,
                                                      const u16* __restrict__ wbt,
                                                      float* __restrict__ out) {
  __shared__ u16 lds[2 * 32768];  // 128 KiB: per buffer A[256][64] + B[256][64]

  // XCD swizzle, chunked 4Mx8N per concurrent 32-block round (nwg=512, 512%8==0)
  const int bid  = blockIdx.x;
  const int xcd  = bid & 7;
  const int idx  = bid >> 3;            // 0..63 within XCD
  const int mtl  = (idx >> 3) & 3;      // 4 M-tiles per XCD
  const int ntl  = (idx & 7) | ((idx >> 5) << 3);  // 8 N-tiles per round, 2 rounds
  const int brow = (xcd * 4 + mtl) * 256;
  const int bcol = ntl * 256;

  const int tid  = threadIdx.x;
  const int lane = tid & 63;
  const int wid  = tid >> 6;   // 0..7
  const int wr   = wid >> 2;   // 0..1
  const int wc   = wid & 3;    // 0..3
  const int l31  = lane & 31;
  const int hi   = lane >> 5;  // 0..1
  const int l7   = lane & 7;

  // staging geometry: wave-instr (wid,j) covers half-tile rows wid*16+j*8 .. +8
  // LDS dest linear (base + lane*16); global source pre-swizzled: chunk = (lane&7) ^ (row&7)
  const int srow0 = wid * 16 + (lane >> 3);
  const int srow1 = srow0 + 8;
  const u16* gA0 = xb  + (size_t)(brow + srow0) * KP + ((lane & 7) ^ (srow0 & 7)) * 8;
  const u16* gA1 = xb  + (size_t)(brow + srow1) * KP + ((lane & 7) ^ (srow1 & 7)) * 8;
  const u16* gB0 = wbt + (size_t)(bcol + srow0) * KP + ((lane & 7) ^ (srow0 & 7)) * 8;
  const u16* gB1 = wbt + (size_t)(bcol + srow1) * KP + ((lane & 7) ^ (srow1 & 7)) * 8;
  const int dst0 = wid * 1024;        // u16 elems within half-region
  const int dst1 = dst0 + 512;

// stage half-tile H (0,1 = A halves; 2,3 = B halves) of K-tile U into buf (U&1)
#define STGH(U, H) do {                                                              \
    u16* _lb = lds + ((U) & 1) * 32768 + ((H) < 2 ? 0 : 16384) + ((H) & 1) * 8192;   \
    size_t _ko = (size_t)(U) * 64 + (size_t)((H) & 1) * 128 * KP;                    \
    if ((H) < 2) { GLOAD(gA0 + _ko, _lb + dst0); GLOAD(gA1 + _ko, _lb + dst1); }     \
    else         { GLOAD(gB0 + _ko, _lb + dst0); GLOAD(gB1 + _ko, _lb + dst1); }     \
  } while (0)

// swizzled ds_read_b128 of one 32x32x16 MFMA fragment:
//   A: row = lane&31 of frag, k = (lane>>5)*8 + e  (natural extension of verified 16x16x32 map)
#define RD32_A(mi, ks) (*reinterpret_cast<const bf16x8*>(bufA + (wr * 128 + (mi) * 32 + l31) * 64 + ((((ks) * 2 + hi) ^ l7) * 8)))
#define RD32_B(ni, ks) (*reinterpret_cast<const bf16x8*>(bufB + (wc * 64  + (ni) * 32 + l31) * 64 + ((((ks) * 2 + hi) ^ l7) * 8)))

// read A-frags (mi0, mi0+1), all 4 k-steps, into a_[0..1][0..3]  (8 x ds_read_b128)
#define RDA_PAIR(mi0) do {                                                           \
    _Pragma("unroll") for (int _k = 0; _k < 4; ++_k) {                               \
      a_[0][_k] = RD32_A((mi0), _k); a_[1][_k] = RD32_A((mi0) + 1, _k); }            \
  } while (0)
// read B-frag ni, all 4 k-steps (4 x ds_read_b128)
#define RDB_ONE(ni) do {                                                             \
    _Pragma("unroll") for (int _k = 0; _k < 4; ++_k) b_[ni][_k] = RD32_B((ni), _k);  \
  } while (0)

// one phase: 2 M-frags x 1 N-frag x K=64 -> 8 MFMA into acc[M0], acc[M1] (literal idx)
#define QUAD32(M0, M1, NI) do {                                                      \
    __builtin_amdgcn_s_setprio(1);                                                   \
    _Pragma("unroll") for (int _k = 0; _k < 4; ++_k) {                               \
      acc[M0][NI] = __builtin_amdgcn_mfma_f32_32x32x16_bf16(a_[0][_k], b_[NI][_k], acc[M0][NI], 0, 0, 0); \
      acc[M1][NI] = __builtin_amdgcn_mfma_f32_32x32x16_bf16(a_[1][_k], b_[NI][_k], acc[M1][NI], 0, 0, 0); \
    }                                                                                \
    __builtin_amdgcn_s_setprio(0);                                                   \
  } while (0)

  f32x16 acc[4][2] = {};
  bf16x8 a_[2][4], b_[2][4];
  const u16 *bufA, *bufB;

  // prologue: tile0 fully (8 loads) + tile1 h0 (2 loads, in flight across fence)
  STGH(0, 0); STGH(0, 1); STGH(0, 2); STGH(0, 3);
  STGH(1, 0);
  asm volatile("s_waitcnt vmcnt(2)" ::: "memory");
  bar();

  // round-2 staging schedule (fine interleave): ph1 h1, ph2 h2, ph3 h3, ph4 h0(next) + vmcnt(2)
  for (int t = 0; t < NT - 1; t += 2) {
    // ---------------- tile t (buf 0) ----------------
    bufA = lds; bufB = lds + 16384;
    RDA_PAIR(0); RDB_ONE(0);
    STGH(t + 1, 1);
    bar(); QUAD32(0, 1, 0); bar();

    RDB_ONE(1);
    STGH(t + 1, 2);
    bar(); QUAD32(0, 1, 1); bar();

    RDA_PAIR(2);
    STGH(t + 1, 3);
    bar(); QUAD32(2, 3, 1); bar();

    STGH(t + 2, 0);
    asm volatile("s_waitcnt vmcnt(2)" ::: "memory");   // tile t+1 fully resident
    bar(); QUAD32(2, 3, 0); bar();

    // ---------------- tile t+1 (buf 1) ----------------
    bufA = lds + 32768; bufB = bufA + 16384;
    RDA_PAIR(0); RDB_ONE(0);
    STGH(t + 2, 1);
    bar(); QUAD32(0, 1, 0); bar();

    RDB_ONE(1);
    STGH(t + 2, 2);
    bar(); QUAD32(0, 1, 1); bar();

    RDA_PAIR(2);
    STGH(t + 2, 3);
    bar(); QUAD32(2, 3, 1); bar();

    if (t + 3 < NT) {
      STGH(t + 3, 0);
      asm volatile("s_waitcnt vmcnt(2)" ::: "memory"); // tile t+2 fully resident
    } else {
      asm volatile("s_waitcnt vmcnt(0)" ::: "memory"); // last: drain everything
    }
    bar(); QUAD32(2, 3, 0); bar();
  }

  // ---------------- tail tile NT-1 = 68 (buf 0), fully resident ----------------
  bufA = lds; bufB = lds + 16384;
  RDA_PAIR(0); RDB_ONE(0); QUAD32(0, 1, 0);
  RDB_ONE(1);              QUAD32(0, 1, 1);
  RDA_PAIR(2);             QUAD32(2, 3, 1); QUAD32(2, 3, 0);

  // epilogue: 32x32 C/D layout (m74/m101): col = lane&31, row = (r&3) + 8*(r>>2) + 4*hi
  const int r0 = brow + wr * 128;
  const int c0 = bcol + wc * 64 + l31;
#pragma unroll
  for (int mi = 0; mi < 4; ++mi)
#pragma unroll
    for (int ni = 0; ni < 2; ++ni)
#pragma unroll
      for (int r = 0; r < 16; ++r) {
        const int row = r0 + mi * 32 + (r & 3) + 8 * (r >> 2) + 4 * hi;
        out[(size_t)row * NDIM + c0 + ni * 32] = acc[mi][ni][r];
      }
}

// ---------------- fallback (ws too small): correct fp32 path ----------------
__global__ void fallback_kernel(const float* __restrict__ z, const float* __restrict__ W,
                                const float* __restrict__ bias, float* __restrict__ out) {
  __shared__ float feat[KREAL];
  const int row = blockIdx.x;
  const int tid = threadIdx.x;
  for (int t = tid; t < KREAL; t += 256) {
    float v;
    if (t == 0) v = 1.0f;
    else if (t < 17) v = z[row * 16 + t - 1];
    else if (t < 273) { int u = t - 17; v = z[row * 16 + (u >> 4)] * z[row * 16 + (u & 15)]; }
    else { int u = t - 273; v = z[row * 16 + ((u >> 8) & 15)] * (z[row * 16 + ((u >> 4) & 15)] * z[row * 16 + (u & 15)]); }
    feat[t] = v;
  }
  __syncthreads();
  float acc[16];
#pragma unroll
  for (int j = 0; j < 16; ++j) acc[j] = bias[tid + 256 * j];
  for (int t = 0; t < KREAL; ++t) {
    const float fv = feat[t];
    const float* wrow = W + (size_t)t * NDIM;
#pragma unroll
    for (int j = 0; j < 16; ++j) acc[j] = fmaf(fv, wrow[tid + 256 * j], acc[j]);
  }
  float* orow = out + (size_t)row * NDIM;
#pragma unroll
  for (int j = 0; j < 16; ++j) orow[tid + 256 * j] = acc[j];
}

extern "C" void kernel_launch(void* const* d_in, const int* in_sizes, int n_in,
                              void* d_out, int out_size, void* d_ws, size_t ws_size,
                              hipStream_t stream) {
  const float* z = (const float*)d_in[0];
  const float* W = (const float*)d_in[1];
  const float* b = (const float*)d_in[2];
  float* out = (float*)d_out;

  const size_t xb_elems  = (size_t)MROWS * KP;
  const size_t wbt_elems = (size_t)NDIM * KP;
  const size_t need = (xb_elems + wbt_elems) * sizeof(u16);

  if (ws_size >= need) {
    u16* xb  = (u16*)d_ws;
    u16* wbt = xb + xb_elems;
    feat_kernel<<<MROWS, 256, 0, stream>>>(z, xb);
    wconv_kernel<<<dim3(KP / 64, NDIM / 64), 256, 0, stream>>>(W, b, wbt);
    gemm_kernel<<<(MROWS / 256) * (NDIM / 256), 512, 0, stream>>>(xb, wbt, out);
  } else {
    fallback_kernel<<<MROWS, 256, 0, stream>>>(z, W, b, out);
  }
}

// Round 5
// 298.092 us; speedup vs baseline: 1.0968x; 1.0968x over previous
//
#include <hip/hip_runtime.h>
#include <hip/hip_bf16.h>

#define KREAL 4369
#define KP    4416   // 69 * 64
#define NT    69     // K-tiles of 64
#define NDIM  4096
#define MROWS 8192

typedef unsigned short u16;
typedef __attribute__((ext_vector_type(8))) __bf16 bf16x8;
typedef __attribute__((ext_vector_type(8))) u16 u16x8;
typedef __attribute__((ext_vector_type(4))) float f32x4;

__device__ __forceinline__ u16 bf16rne(float f) {
  unsigned int u = __builtin_bit_cast(unsigned int, f);
  u += 0x7fffu + ((u >> 16) & 1u);
  return (u16)(u >> 16);
}

// ---------------- feature kernel: xb[row][t] = bf16(polyfeat(z_row)[t]) ----------------
__global__ void feat_kernel(const float* __restrict__ z, u16* __restrict__ xb) {
  __shared__ float zs[16];
  const int row = blockIdx.x;
  const int tid = threadIdx.x;
  if (tid < 16) zs[tid] = z[row * 16 + tid];
  __syncthreads();
  u16* xrow = xb + (size_t)row * KP;
  for (int g = tid; g < KP / 8; g += 256) {
    u16x8 pack;
#pragma unroll
    for (int e = 0; e < 8; ++e) {
      int t = g * 8 + e;
      float v;
      if (t >= KREAL) v = 0.0f;
      else if (t == 0) v = 1.0f;
      else if (t < 17) v = zs[t - 1];
      else if (t < 273) { int u = t - 17; v = zs[u >> 4] * zs[u & 15]; }
      else { int u = t - 273; v = zs[(u >> 8) & 15] * (zs[(u >> 4) & 15] * zs[u & 15]); }
      pack[e] = bf16rne(v);
    }
    *reinterpret_cast<u16x8*>(xrow + g * 8) = pack;
  }
}

// ------- W convert+transpose: wbt[d][t] = bf16(W[t][d] + (t==0 ? b[d] : 0)), t>=KREAL -> 0 -------
__global__ void wconv_kernel(const float* __restrict__ W, const float* __restrict__ bias,
                             u16* __restrict__ wbt) {
  __shared__ float tile[64][68];
  const int t0 = blockIdx.x * 64;
  const int d0 = blockIdx.y * 64;
  const int tid = threadIdx.x;
  const int d4 = (tid & 15) * 4;   // float4 column within tile
  const int rb = tid >> 4;         // 0..15
#pragma unroll
  for (int p = 0; p < 4; ++p) {
    const int r = p * 16 + rb;
    const int t = t0 + r;
    f32x4 v = {0.f, 0.f, 0.f, 0.f};
    if (t < KREAL) {
      v = *reinterpret_cast<const f32x4*>(W + (size_t)t * NDIM + d0 + d4);
      if (t == 0) {
        f32x4 bb = *reinterpret_cast<const f32x4*>(bias + d0 + d4);
        v.x += bb.x; v.y += bb.y; v.z += bb.z; v.w += bb.w;
      }
    }
#pragma unroll
    for (int j = 0; j < 4; ++j) tile[r][d4 + j] = v[j];
  }
  __syncthreads();
#pragma unroll
  for (int round = 0; round < 2; ++round) {
    const int v = round * 256 + tid;
    const int d = v >> 3;   // 0..63
    const int tg = v & 7;   // 0..7
    u16x8 pack;
#pragma unroll
    for (int e = 0; e < 8; ++e) pack[e] = bf16rne(tile[tg * 8 + e][d]);
    *reinterpret_cast<u16x8*>(wbt + (size_t)(d0 + d) * KP + t0 + tg * 8) = pack;
  }
}

// ---------------- 256x256 8-phase GEMM, depth-3 prefetch: out = xb @ wbt^T ----------------
#define GLOAD(gp, lp)                                                                     \
  __builtin_amdgcn_global_load_lds((const __attribute__((address_space(1))) unsigned int*)(gp), \
                                   (__attribute__((address_space(3))) unsigned int*)(lp), 16, 0, 0)

__device__ __forceinline__ void bar() {
  asm volatile("" ::: "memory");
  __builtin_amdgcn_s_barrier();
  asm volatile("" ::: "memory");
}

__global__ __launch_bounds__(512, 2) void gemm_kernel(const u16* __restrict__ xb,
                                                      const u16* __restrict__ wbt,
                                                      float* __restrict__ out) {
  __shared__ u16 lds[2 * 32768];  // 128 KiB: per buffer A[256][64] + B[256][64]

  // XCD swizzle, chunked 4Mx8N per concurrent 32-block round (nwg=512, 512%8==0)
  const int bid  = blockIdx.x;
  const int xcd  = bid & 7;
  const int idx  = bid >> 3;            // 0..63 within XCD
  const int mtl  = (idx >> 3) & 3;      // 4 M-tiles per XCD
  const int ntl  = (idx & 7) | ((idx >> 5) << 3);  // 8 N-tiles per round, 2 rounds
  const int brow = (xcd * 4 + mtl) * 256;
  const int bcol = ntl * 256;

  const int tid  = threadIdx.x;
  const int lane = tid & 63;
  const int wid  = tid >> 6;   // 0..7
  const int wr   = wid >> 2;   // 0..1
  const int wc   = wid & 3;    // 0..3
  const int f    = lane & 15;
  const int q    = lane >> 4;
  const int f7   = f & 7;

  // staging: each global_load_lds covers 8 contiguous LDS rows (lane>>3) x 8 chunks (lane&7),
  // LDS dest linear; global source pre-swizzled chunk = (lane&7) ^ (lane>>3)  (row%8 == lane>>3)
  const int lr = lane >> 3;                         // row-in-group 0..7
  const int lc = ((lane & 7) ^ lr) * 8;             // pre-swizzled source chunk (u16 elems)
  const u16* gA = xb  + (size_t)(brow + lr) * KP + lc;
  const u16* gB = wbt + (size_t)(bcol + lr) * KP + lc;

  // part base rows (each part = 2 instrs: rows R0..R0+7 and R0+8..R0+15)
  const int aR0 = (wid >> 2) * 128 + (wid & 3) * 16;   // A-P0; A-P1 = +64
  const int bR0 = (wid & 3) * 64 + (wid >> 2) * 16;    // B-P0; B-P1 = +32

// stage one part (2 x global_load_lds) of K-tile U: gptr in {gA,gB}, lbase = buf + (B?16384:0)
#define STG2(gptr, lbase, R0, U) do {                                              \
    GLOAD((gptr) + (size_t)(R0) * KP + (size_t)(U) * 64, (lbase) + (R0) * 64);     \
    GLOAD((gptr) + (size_t)((R0) + 8) * KP + (size_t)(U) * 64, (lbase) + ((R0) + 8) * 64); \
  } while (0)

// swizzled ds_read_b128 of one 16x16x32 MFMA fragment (proven 0-conflict pattern)
#define RD_A(mi, kk) (*reinterpret_cast<const bf16x8*>(bufA + (wr * 128 + (mi) * 16 + f) * 64 + (((kk) * 4 + q) ^ f7) * 8))
#define RD_B(ni, kk) (*reinterpret_cast<const bf16x8*>(bufB + (wc * 64 + (ni) * 16 + f) * 64 + (((kk) * 4 + q) ^ f7) * 8))

#define RDA4(MOFF) do {                                                              \
    _Pragma("unroll") for (int _i = 0; _i < 4; ++_i) {                               \
      a_[_i][0] = RD_A((MOFF) + _i, 0); a_[_i][1] = RD_A((MOFF) + _i, 1); }          \
  } while (0)
#define RDB2(NOFF) do {                                                              \
    _Pragma("unroll") for (int _i = 0; _i < 2; ++_i) {                               \
      b_[(NOFF) + _i][0] = RD_B((NOFF) + _i, 0); b_[(NOFF) + _i][1] = RD_B((NOFF) + _i, 1); } \
  } while (0)

// one C-quadrant (4 M-frags x 2 N-frags x K=64) = 16 MFMA, setprio-wrapped (T5)
#define QUAD(MOFF, NOFF) do {                                                        \
    __builtin_amdgcn_s_setprio(1);                                                   \
    _Pragma("unroll") for (int _m = 0; _m < 4; ++_m)                                 \
    _Pragma("unroll") for (int _n = 0; _n < 2; ++_n)                                 \
    _Pragma("unroll") for (int _k = 0; _k < 2; ++_k)                                 \
      acc[(MOFF) + _m][(NOFF) + _n] = __builtin_amdgcn_mfma_f32_16x16x32_bf16(       \
          a_[_m][_k], b_[(NOFF) + _n][_k], acc[(MOFF) + _m][(NOFF) + _n], 0, 0, 0);  \
    __builtin_amdgcn_s_setprio(0);                                                   \
  } while (0)

  f32x4 acc[8][4] = {};
  bf16x8 a_[4][2], b_[4][2];

  u16* buf0 = lds;
  u16* buf1 = lds + 32768;

  // prologue: tile0 all 4 parts into buf0; tile1 A-P0, B-P0, A-P1 into buf1 (B-P1(1) comes at t=0 ph1)
  STG2(gA, buf0, aR0, 0); STG2(gB, buf0 + 16384, bR0, 0);
  STG2(gB, buf0 + 16384, bR0 + 32, 0); STG2(gA, buf0, aR0 + 64, 0);
  STG2(gA, buf1, aR0, 1); STG2(gB, buf1 + 16384, bR0, 1); STG2(gA, buf1, aR0 + 64, 1);
  asm volatile("s_waitcnt vmcnt(6)" ::: "memory");   // tile0 resident; tile1's 3 parts in flight
  bar();

  // per tile t: ph1 stage B-P1(t+1); ph2 A-P0(t+2); ph3 B-P0(t+2); ph4 A-P1(t+2) + vmcnt(6)
  // region safety: each staged region's last ds_read retired at a barrier >=1 phase earlier
  for (int t = 0; t < NT - 1; ++t) {
    const u16* bufA = (t & 1) ? buf1 : buf0;
    const u16* bufB = bufA + 16384;
    u16* nb = (t & 1) ? buf0 : buf1;   // buf of tile t+1
    u16* cb = (u16*)bufA;              // buf of tile t+2 (same parity as t)

    // ph1: reads A-P0 frags + B-P0 frags
    RDA4(0); RDB2(0);
    STG2(gB, nb + 16384, bR0 + 32, t + 1);           // B-P1(t+1)
    bar(); QUAD(0, 0); bar();

    // ph2: reads B-P1 frags
    RDB2(2);
    if (t + 2 < NT) STG2(gA, cb, aR0, t + 2);        // A-P0(t+2)
    bar(); QUAD(0, 2); bar();

    // ph3: reads A-P1 frags
    RDA4(4);
    if (t + 2 < NT) STG2(gB, cb + 16384, bR0, t + 2);// B-P0(t+2)
    bar(); QUAD(4, 2); bar();

    // ph4
    if (t + 2 < NT) {
      STG2(gA, cb, aR0 + 64, t + 2);                 // A-P1(t+2)
      asm volatile("s_waitcnt vmcnt(6)" ::: "memory"); // tile t+1 fully resident
    } else {
      asm volatile("s_waitcnt vmcnt(0)" ::: "memory"); // drain for final tile
    }
    bar(); QUAD(4, 0); bar();
  }

  // tail tile NT-1 = 68 (buf0), fully resident
  {
    const u16* bufA = buf0;
    const u16* bufB = buf0 + 16384;
    RDA4(0); RDB2(0); QUAD(0, 0);
    RDB2(2);          QUAD(0, 2);
    RDA4(4);          QUAD(4, 2); QUAD(4, 0);
  }

  // epilogue: C/D layout col = lane&15, row = (lane>>4)*4 + j
  const int r0 = brow + wr * 128 + q * 4;
  const int c0 = bcol + wc * 64 + f;
#pragma unroll
  for (int mi = 0; mi < 8; ++mi)
#pragma unroll
    for (int ni = 0; ni < 4; ++ni) {
#pragma unroll
      for (int j = 0; j < 4; ++j)
        out[(size_t)(r0 + mi * 16 + j) * NDIM + (c0 + ni * 16)] = acc[mi][ni][j];
    }
}

// ---------------- fallback (ws too small): correct fp32 path ----------------
__global__ void fallback_kernel(const float* __restrict__ z, const float* __restrict__ W,
                                const float* __restrict__ bias, float* __restrict__ out) {
  __shared__ float feat[KREAL];
  const int row = blockIdx.x;
  const int tid = threadIdx.x;
  for (int t = tid; t < KREAL; t += 256) {
    float v;
    if (t == 0) v = 1.0f;
    else if (t < 17) v = z[row * 16 + t - 1];
    else if (t < 273) { int u = t - 17; v = z[row * 16 + (u >> 4)] * z[row * 16 + (u & 15)]; }
    else { int u = t - 273; v = z[row * 16 + ((u >> 8) & 15)] * (z[row * 16 + ((u >> 4) & 15)] * z[row * 16 + (u & 15)]); }
    feat[t] = v;
  }
  __syncthreads();
  float acc[16];
#pragma unroll
  for (int j = 0; j < 16; ++j) acc[j] = bias[tid + 256 * j];
  for (int t = 0; t < KREAL; ++t) {
    const float fv = feat[t];
    const float* wrow = W + (size_t)t * NDIM;
#pragma unroll
    for (int j = 0; j < 16; ++j) acc[j] = fmaf(fv, wrow[tid + 256 * j], acc[j]);
  }
  float* orow = out + (size_t)row * NDIM;
#pragma unroll
  for (int j = 0; j < 16; ++j) orow[tid + 256 * j] = acc[j];
}

extern "C" void kernel_launch(void* const* d_in, const int* in_sizes, int n_in,
                              void* d_out, int out_size, void* d_ws, size_t ws_size,
                              hipStream_t stream) {
  const float* z = (const float*)d_in[0];
  const float* W = (const float*)d_in[1];
  const float* b = (const float*)d_in[2];
  float* out = (float*)d_out;

  const size_t xb_elems  = (size_t)MROWS * KP;
  const size_t wbt_elems = (size_t)NDIM * KP;
  const size_t need = (xb_elems + wbt_elems) * sizeof(u16);

  if (ws_size >= need) {
    u16* xb  = (u16*)d_ws;
    u16* wbt = xb + xb_elems;
    feat_kernel<<<MROWS, 256, 0, stream>>>(z, xb);
    wconv_kernel<<<dim3(KP / 64, NDIM / 64), 256, 0, stream>>>(W, b, wbt);
    gemm_kernel<<<(MROWS / 256) * (NDIM / 256), 512, 0, stream>>>(xb, wbt, out);
  } else {
    fallback_kernel<<<MROWS, 256, 0, stream>>>(z, W, b, out);
  }
}

// Round 6
// 292.095 us; speedup vs baseline: 1.1193x; 1.0205x over previous
//
#include <hip/hip_runtime.h>
#include <hip/hip_bf16.h>

#define KREAL 4369
#define KP    4416   // 69 * 64
#define NT    69     // K-tiles of 64
#define NDIM  4096
#define MROWS 8192

typedef unsigned short u16;
typedef __attribute__((ext_vector_type(8))) __bf16 bf16x8;
typedef __attribute__((ext_vector_type(8))) u16 u16x8;
typedef __attribute__((ext_vector_type(4))) float f32x4;

__device__ __forceinline__ u16 bf16rne(float f) {
  unsigned int u = __builtin_bit_cast(unsigned int, f);
  u += 0x7fffu + ((u >> 16) & 1u);
  return (u16)(u >> 16);
}

// ---------------- feature kernel: xb[row][t] = bf16(polyfeat(z_row)[t]) ----------------
__global__ void feat_kernel(const float* __restrict__ z, u16* __restrict__ xb) {
  __shared__ float zs[16];
  const int row = blockIdx.x;
  const int tid = threadIdx.x;
  if (tid < 16) zs[tid] = z[row * 16 + tid];
  __syncthreads();
  u16* xrow = xb + (size_t)row * KP;
  for (int g = tid; g < KP / 8; g += 256) {
    u16x8 pack;
#pragma unroll
    for (int e = 0; e < 8; ++e) {
      int t = g * 8 + e;
      float v;
      if (t >= KREAL) v = 0.0f;
      else if (t == 0) v = 1.0f;
      else if (t < 17) v = zs[t - 1];
      else if (t < 273) { int u = t - 17; v = zs[u >> 4] * zs[u & 15]; }
      else { int u = t - 273; v = zs[(u >> 8) & 15] * (zs[(u >> 4) & 15] * zs[u & 15]); }
      pack[e] = bf16rne(v);
    }
    *reinterpret_cast<u16x8*>(xrow + g * 8) = pack;
  }
}

// ------- W convert+transpose: wbt[d][t] = bf16(W[t][d] + (t==0 ? b[d] : 0)), t>=KREAL -> 0 -------
__global__ void wconv_kernel(const float* __restrict__ W, const float* __restrict__ bias,
                             u16* __restrict__ wbt) {
  __shared__ float tile[64][68];
  const int t0 = blockIdx.x * 64;
  const int d0 = blockIdx.y * 64;
  const int tid = threadIdx.x;
  const int d4 = (tid & 15) * 4;   // float4 column within tile
  const int rb = tid >> 4;         // 0..15
#pragma unroll
  for (int p = 0; p < 4; ++p) {
    const int r = p * 16 + rb;
    const int t = t0 + r;
    f32x4 v = {0.f, 0.f, 0.f, 0.f};
    if (t < KREAL) {
      v = *reinterpret_cast<const f32x4*>(W + (size_t)t * NDIM + d0 + d4);
      if (t == 0) {
        f32x4 bb = *reinterpret_cast<const f32x4*>(bias + d0 + d4);
        v.x += bb.x; v.y += bb.y; v.z += bb.z; v.w += bb.w;
      }
    }
#pragma unroll
    for (int j = 0; j < 4; ++j) tile[r][d4 + j] = v[j];
  }
  __syncthreads();
#pragma unroll
  for (int round = 0; round < 2; ++round) {
    const int v = round * 256 + tid;
    const int d = v >> 3;   // 0..63
    const int tg = v & 7;   // 0..7
    u16x8 pack;
#pragma unroll
    for (int e = 0; e < 8; ++e) pack[e] = bf16rne(tile[tg * 8 + e][d]);
    *reinterpret_cast<u16x8*>(wbt + (size_t)(d0 + d) * KP + t0 + tg * 8) = pack;
  }
}

// ---------------- 256x256 8-phase GEMM (R2 schedule + chunked XCD swizzle) ----------------
#define GLOAD(gp, lp)                                                                     \
  __builtin_amdgcn_global_load_lds((const __attribute__((address_space(1))) unsigned int*)(gp), \
                                   (__attribute__((address_space(3))) unsigned int*)(lp), 16, 0, 0)

__device__ __forceinline__ void bar() {
  asm volatile("" ::: "memory");
  __builtin_amdgcn_s_barrier();
  asm volatile("" ::: "memory");
}

__global__ __launch_bounds__(512, 2) void gemm_kernel(const u16* __restrict__ xb,
                                                      const u16* __restrict__ wbt,
                                                      float* __restrict__ out) {
  __shared__ u16 lds[2 * 32768];  // 128 KiB: per buffer A[256][64] + B[256][64]

  // XCD swizzle, chunked 4Mx8N per concurrent 32-block round (nwg=512, 512%8==0)
  const int bid  = blockIdx.x;
  const int xcd  = bid & 7;
  const int idx  = bid >> 3;            // 0..63 within XCD
  const int mtl  = (idx >> 3) & 3;      // 4 M-tiles per XCD
  const int ntl  = (idx & 7) | ((idx >> 5) << 3);  // 8 N-tiles per round, 2 rounds
  const int brow = (xcd * 4 + mtl) * 256;
  const int bcol = ntl * 256;

  const int tid  = threadIdx.x;
  const int lane = tid & 63;
  const int wid  = tid >> 6;   // 0..7
  const int wr   = wid >> 2;   // 0..1
  const int wc   = wid & 3;    // 0..3
  const int f    = lane & 15;
  const int q    = lane >> 4;
  const int f7   = f & 7;

  // staging geometry: wave-instr (wid,j) covers half-tile rows wid*16+j*8 .. +8
  // LDS dest linear (base + lane*16); global source pre-swizzled: chunk = (lane&7) ^ (row&7)
  const int srow0 = wid * 16 + (lane >> 3);
  const int srow1 = srow0 + 8;
  const u16* gA0 = xb  + (size_t)(brow + srow0) * KP + ((lane & 7) ^ (srow0 & 7)) * 8;
  const u16* gA1 = xb  + (size_t)(brow + srow1) * KP + ((lane & 7) ^ (srow1 & 7)) * 8;
  const u16* gB0 = wbt + (size_t)(bcol + srow0) * KP + ((lane & 7) ^ (srow0 & 7)) * 8;
  const u16* gB1 = wbt + (size_t)(bcol + srow1) * KP + ((lane & 7) ^ (srow1 & 7)) * 8;
  const int dst0 = wid * 1024;        // u16 elems within half-region
  const int dst1 = dst0 + 512;

// stage half-tile H (0,1 = A halves; 2,3 = B halves) of K-tile U into buf (U&1)
#define STGH(U, H) do {                                                              \
    u16* _lb = lds + ((U) & 1) * 32768 + ((H) < 2 ? 0 : 16384) + ((H) & 1) * 8192;   \
    size_t _ko = (size_t)(U) * 64 + (size_t)((H) & 1) * 128 * KP;                    \
    if ((H) < 2) { GLOAD(gA0 + _ko, _lb + dst0); GLOAD(gA1 + _ko, _lb + dst1); }     \
    else         { GLOAD(gB0 + _ko, _lb + dst0); GLOAD(gB1 + _ko, _lb + dst1); }     \
  } while (0)

// swizzled ds_read_b128 of one MFMA fragment (proven 0-conflict pattern)
#define RD_A(mi, kk) (*reinterpret_cast<const bf16x8*>(bufA + (wr * 128 + (mi) * 16 + f) * 64 + (((kk) * 4 + q) ^ f7) * 8))
#define RD_B(ni, kk) (*reinterpret_cast<const bf16x8*>(bufB + (wc * 64 + (ni) * 16 + f) * 64 + (((kk) * 4 + q) ^ f7) * 8))

#define RDA4(MOFF) do {                                                              \
    _Pragma("unroll") for (int _i = 0; _i < 4; ++_i) {                               \
      a_[_i][0] = RD_A((MOFF) + _i, 0); a_[_i][1] = RD_A((MOFF) + _i, 1); }          \
  } while (0)
#define RDB2(NOFF) do {                                                              \
    _Pragma("unroll") for (int _i = 0; _i < 2; ++_i) {                               \
      b_[(NOFF) + _i][0] = RD_B((NOFF) + _i, 0); b_[(NOFF) + _i][1] = RD_B((NOFF) + _i, 1); } \
  } while (0)

// one C-quadrant (4 M-frags x 2 N-frags x K=64) = 16 MFMA, setprio-wrapped (T5)
#define QUAD(MOFF, NOFF) do {                                                        \
    __builtin_amdgcn_s_setprio(1);                                                   \
    _Pragma("unroll") for (int _m = 0; _m < 4; ++_m)                                 \
    _Pragma("unroll") for (int _n = 0; _n < 2; ++_n)                                 \
    _Pragma("unroll") for (int _k = 0; _k < 2; ++_k)                                 \
      acc[(MOFF) + _m][(NOFF) + _n] = __builtin_amdgcn_mfma_f32_16x16x32_bf16(       \
          a_[_m][_k], b_[(NOFF) + _n][_k], acc[(MOFF) + _m][(NOFF) + _n], 0, 0, 0);  \
    __builtin_amdgcn_s_setprio(0);                                                   \
  } while (0)

  f32x4 acc[8][4] = {};
  bf16x8 a_[4][2], b_[4][2];
  const u16 *bufA, *bufB;

  // prologue: tile0 fully (8 loads) + tile1 h0 (2 loads, in flight across fence)
  STGH(0, 0); STGH(0, 1); STGH(0, 2); STGH(0, 3);
  STGH(1, 0);
  asm volatile("s_waitcnt vmcnt(2)" ::: "memory");
  bar();

  // R2 staging schedule (fine interleave): ph1 h1, ph2 h2, ph3 h3, ph4 h0(next) + vmcnt(2)
  for (int t = 0; t < NT - 1; t += 2) {
    // ---------------- tile t (buf 0) ----------------
    bufA = lds; bufB = lds + 16384;
    RDA4(0); RDB2(0);
    STGH(t + 1, 1);
    bar(); QUAD(0, 0); bar();

    RDB2(2);
    STGH(t + 1, 2);
    bar(); QUAD(0, 2); bar();

    RDA4(4);
    STGH(t + 1, 3);
    bar(); QUAD(4, 2); bar();

    STGH(t + 2, 0);
    asm volatile("s_waitcnt vmcnt(2)" ::: "memory");   // tile t+1 fully resident
    bar(); QUAD(4, 0); bar();

    // ---------------- tile t+1 (buf 1) ----------------
    bufA = lds + 32768; bufB = bufA + 16384;
    RDA4(0); RDB2(0);
    STGH(t + 2, 1);
    bar(); QUAD(0, 0); bar();

    RDB2(2);
    STGH(t + 2, 2);
    bar(); QUAD(0, 2); bar();

    RDA4(4);
    STGH(t + 2, 3);
    bar(); QUAD(4, 2); bar();

    if (t + 3 < NT) {
      STGH(t + 3, 0);
      asm volatile("s_waitcnt vmcnt(2)" ::: "memory"); // tile t+2 fully resident
    } else {
      asm volatile("s_waitcnt vmcnt(0)" ::: "memory"); // last: drain everything
    }
    bar(); QUAD(4, 0); bar();
  }

  // ---------------- tail tile NT-1 = 68 (buf 0), fully resident ----------------
  bufA = lds; bufB = lds + 16384;
  RDA4(0); RDB2(0); QUAD(0, 0);
  RDB2(2);          QUAD(0, 2);
  RDA4(4);          QUAD(4, 2); QUAD(4, 0);

  // epilogue: C/D layout col = lane&15, row = (lane>>4)*4 + j
  const int r0 = brow + wr * 128 + q * 4;
  const int c0 = bcol + wc * 64 + f;
#pragma unroll
  for (int mi = 0; mi < 8; ++mi)
#pragma unroll
    for (int ni = 0; ni < 4; ++ni) {
#pragma unroll
      for (int j = 0; j < 4; ++j)
        out[(size_t)(r0 + mi * 16 + j) * NDIM + (c0 + ni * 16)] = acc[mi][ni][j];
    }
}

// ---------------- fallback (ws too small): correct fp32 path ----------------
__global__ void fallback_kernel(const float* __restrict__ z, const float* __restrict__ W,
                                const float* __restrict__ bias, float* __restrict__ out) {
  __shared__ float feat[KREAL];
  const int row = blockIdx.x;
  const int tid = threadIdx.x;
  for (int t = tid; t < KREAL; t += 256) {
    float v;
    if (t == 0) v = 1.0f;
    else if (t < 17) v = z[row * 16 + t - 1];
    else if (t < 273) { int u = t - 17; v = z[row * 16 + (u >> 4)] * z[row * 16 + (u & 15)]; }
    else { int u = t - 273; v = z[row * 16 + ((u >> 8) & 15)] * (z[row * 16 + ((u >> 4) & 15)] * z[row * 16 + (u & 15)]); }
    feat[t] = v;
  }
  __syncthreads();
  float acc[16];
#pragma unroll
  for (int j = 0; j < 16; ++j) acc[j] = bias[tid + 256 * j];
  for (int t = 0; t < KREAL; ++t) {
    const float fv = feat[t];
    const float* wrow = W + (size_t)t * NDIM;
#pragma unroll
    for (int j = 0; j < 16; ++j) acc[j] = fmaf(fv, wrow[tid + 256 * j], acc[j]);
  }
  float* orow = out + (size_t)row * NDIM;
#pragma unroll
  for (int j = 0; j < 16; ++j) orow[tid + 256 * j] = acc[j];
}

extern "C" void kernel_launch(void* const* d_in, const int* in_sizes, int n_in,
                              void* d_out, int out_size, void* d_ws, size_t ws_size,
                              hipStream_t stream) {
  const float* z = (const float*)d_in[0];
  const float* W = (const float*)d_in[1];
  const float* b = (const float*)d_in[2];
  float* out = (float*)d_out;

  const size_t xb_elems  = (size_t)MROWS * KP;
  const size_t wbt_elems = (size_t)NDIM * KP;
  const size_t need = (xb_elems + wbt_elems) * sizeof(u16);

  if (ws_size >= need) {
    u16* xb  = (u16*)d_ws;
    u16* wbt = xb + xb_elems;
    feat_kernel<<<MROWS, 256, 0, stream>>>(z, xb);
    wconv_kernel<<<dim3(KP / 64, NDIM / 64), 256, 0, stream>>>(W, b, wbt);
    gemm_kernel<<<(MROWS / 256) * (NDIM / 256), 512, 0, stream>>>(xb, wbt, out);
  } else {
    fallback_kernel<<<MROWS, 256, 0, stream>>>(z, W, b, out);
  }
}

// Round 7
// 181.097 us; speedup vs baseline: 1.8053x; 1.6129x over previous
//
#include <hip/hip_runtime.h>
#include <hip/hip_bf16.h>

#define NDIM  4096
#define MROWS 8192
// folded feature space: 1 + 16 + 136 + 816 = 969 distinct multiset products, padded to 17*64
#define PREAL 969
#define KP    1088   // 17 * 64
#define NT    17

typedef unsigned short u16;
typedef __attribute__((ext_vector_type(8))) __bf16 bf16x8;
typedef __attribute__((ext_vector_type(4))) u16 u16x4;
typedef __attribute__((ext_vector_type(8))) u16 u16x8;
typedef __attribute__((ext_vector_type(4))) float f32x4;

__device__ __forceinline__ u16 bf16rne(float f) {
  unsigned int u = __builtin_bit_cast(unsigned int, f);
  u += 0x7fffu + ((u >> 16) & 1u);
  return (u16)(u >> 16);
}

// -------- map_kernel: table[p] = packed (i<=j<=k), 16 = "identity" (multiply by 1); -1 = pad --------
__global__ void map_kernel(int* __restrict__ table) {
  const int p = blockIdx.x * 256 + threadIdx.x;
  if (p >= KP) return;
  int enc = -1;
  if (p == 0) enc = (16 << 10) | (16 << 5) | 16;
  else if (p < 17) enc = ((p - 1) << 10) | (16 << 5) | 16;
  else if (p < 153) {
    int r = p - 17, cnt = 0;
    for (int i = 0; i < 16 && enc < 0; ++i)
      for (int j = i; j < 16; ++j) {
        if (cnt == r) { enc = (i << 10) | (j << 5) | 16; break; }
        ++cnt;
      }
  } else if (p < PREAL) {
    int r = p - 153, cnt = 0;
    for (int i = 0; i < 16 && enc < 0; ++i)
      for (int j = i; j < 16 && enc < 0; ++j)
        for (int k = j; k < 16; ++k) {
          if (cnt == r) { enc = (i << 10) | (j << 5) | k; break; }
          ++cnt;
        }
  }
  table[p] = enc;
}

// -------- feat_kernel: xb[row][p] = bf16( z_i * z_j * z_k ) for multiset p --------
__global__ void feat_kernel(const float* __restrict__ z, const int* __restrict__ table,
                            u16* __restrict__ xb) {
  __shared__ float zs[17];
  __shared__ int tl[KP];
  const int row = blockIdx.x;
  const int tid = threadIdx.x;
  if (tid < 16) zs[tid] = z[row * 16 + tid];
  if (tid == 16) zs[16] = 1.0f;
  for (int p = tid; p < KP; p += 256) tl[p] = table[p];
  __syncthreads();
  u16* xrow = xb + (size_t)row * KP;
  for (int g = tid; g < KP / 4; g += 256) {
    u16x4 pack;
#pragma unroll
    for (int e = 0; e < 4; ++e) {
      const int enc = tl[g * 4 + e];
      float v = 0.0f;
      if (enc >= 0) v = zs[enc >> 10] * (zs[(enc >> 5) & 31] * zs[enc & 31]);
      pack[e] = bf16rne(v);
    }
    *reinterpret_cast<u16x4*>(xrow + g * 4) = pack;
  }
}

// -------- wfold_kernel: wfbt[d][p] = bf16( sum_{t in perms(p)} W[t][d] + (p==0 ? b[d] : 0) ) --------
__global__ void wfold_kernel(const float* __restrict__ W, const float* __restrict__ bias,
                             const int* __restrict__ table, u16* __restrict__ wfbt) {
  __shared__ float tile[64][68];
  const int p0 = blockIdx.x * 64;
  const int d0 = blockIdx.y * 64;
  const int tid = threadIdx.x;
  const int dloc = tid & 63;
  const int rbase = tid >> 6;  // 0..3
  const int dd = d0 + dloc;
#pragma unroll
  for (int rr = 0; rr < 16; ++rr) {
    const int r = rr * 4 + rbase;
    const int p = p0 + r;
    const int enc = table[p];
    float v = 0.0f;
    if (enc >= 0) {
      const int i = enc >> 10, j = (enc >> 5) & 31, k = enc & 31;
      if (k == 16) {
        if (j == 16) {
          if (i == 16) v = W[dd] + bias[dd];                      // p = 0: constant term
          else         v = W[(size_t)(1 + i) * NDIM + dd];        // degree 1
        } else {                                                  // degree 2, i<=j
          v = W[(size_t)(17 + i * 16 + j) * NDIM + dd];
          if (i != j) v += W[(size_t)(17 + j * 16 + i) * NDIM + dd];
        }
      } else {                                                    // degree 3, i<=j<=k
        v = W[(size_t)(273 + i * 256 + j * 16 + k) * NDIM + dd];
        if (i == j && j == k) {
          // single permutation
        } else if (i == j) {        // i=j<k: (i,i,k),(i,k,i),(k,i,i)
          v += W[(size_t)(273 + i * 256 + k * 16 + i) * NDIM + dd]
             + W[(size_t)(273 + k * 256 + i * 16 + i) * NDIM + dd];
        } else if (j == k) {        // i<j=k: (i,j,j),(j,i,j),(j,j,i)
          v += W[(size_t)(273 + j * 256 + i * 16 + j) * NDIM + dd]
             + W[(size_t)(273 + j * 256 + j * 16 + i) * NDIM + dd];
        } else {                    // all distinct: 6 permutations
          v += W[(size_t)(273 + i * 256 + k * 16 + j) * NDIM + dd]
             + W[(size_t)(273 + j * 256 + i * 16 + k) * NDIM + dd]
             + W[(size_t)(273 + j * 256 + k * 16 + i) * NDIM + dd]
             + W[(size_t)(273 + k * 256 + i * 16 + j) * NDIM + dd]
             + W[(size_t)(273 + k * 256 + j * 16 + i) * NDIM + dd];
        }
      }
    }
    tile[r][dloc] = v;
  }
  __syncthreads();
#pragma unroll
  for (int round = 0; round < 2; ++round) {
    const int v = round * 256 + tid;
    const int d = v >> 3;   // 0..63
    const int tg = v & 7;   // 0..7
    u16x8 pack;
#pragma unroll
    for (int e = 0; e < 8; ++e) pack[e] = bf16rne(tile[tg * 8 + e][d]);
    *reinterpret_cast<u16x8*>(wfbt + (size_t)(d0 + d) * KP + p0 + tg * 8) = pack;
  }
}

// ---------------- 256x256 8-phase GEMM (R2 schedule + chunked XCD swizzle), K=1088 ----------------
#define GLOAD(gp, lp)                                                                     \
  __builtin_amdgcn_global_load_lds((const __attribute__((address_space(1))) unsigned int*)(gp), \
                                   (__attribute__((address_space(3))) unsigned int*)(lp), 16, 0, 0)

__device__ __forceinline__ void bar() {
  asm volatile("" ::: "memory");
  __builtin_amdgcn_s_barrier();
  asm volatile("" ::: "memory");
}

__global__ __launch_bounds__(512, 2) void gemm_kernel(const u16* __restrict__ xb,
                                                      const u16* __restrict__ wbt,
                                                      float* __restrict__ out) {
  __shared__ u16 lds[2 * 32768];  // 128 KiB: per buffer A[256][64] + B[256][64]

  // XCD swizzle, chunked 4Mx8N per concurrent 32-block round (nwg=512, 512%8==0)
  const int bid  = blockIdx.x;
  const int xcd  = bid & 7;
  const int idx  = bid >> 3;            // 0..63 within XCD
  const int mtl  = (idx >> 3) & 3;      // 4 M-tiles per XCD
  const int ntl  = (idx & 7) | ((idx >> 5) << 3);  // 8 N-tiles per round, 2 rounds
  const int brow = (xcd * 4 + mtl) * 256;
  const int bcol = ntl * 256;

  const int tid  = threadIdx.x;
  const int lane = tid & 63;
  const int wid  = tid >> 6;   // 0..7
  const int wr   = wid >> 2;   // 0..1
  const int wc   = wid & 3;    // 0..3
  const int f    = lane & 15;
  const int q    = lane >> 4;
  const int f7   = f & 7;

  // staging geometry: wave-instr (wid,j) covers half-tile rows wid*16+j*8 .. +8
  // LDS dest linear (base + lane*16); global source pre-swizzled: chunk = (lane&7) ^ (row&7)
  const int srow0 = wid * 16 + (lane >> 3);
  const int srow1 = srow0 + 8;
  const u16* gA0 = xb  + (size_t)(brow + srow0) * KP + ((lane & 7) ^ (srow0 & 7)) * 8;
  const u16* gA1 = xb  + (size_t)(brow + srow1) * KP + ((lane & 7) ^ (srow1 & 7)) * 8;
  const u16* gB0 = wbt + (size_t)(bcol + srow0) * KP + ((lane & 7) ^ (srow0 & 7)) * 8;
  const u16* gB1 = wbt + (size_t)(bcol + srow1) * KP + ((lane & 7) ^ (srow1 & 7)) * 8;
  const int dst0 = wid * 1024;        // u16 elems within half-region
  const int dst1 = dst0 + 512;

// stage half-tile H (0,1 = A halves; 2,3 = B halves) of K-tile U into buf (U&1)
#define STGH(U, H) do {                                                              \
    u16* _lb = lds + ((U) & 1) * 32768 + ((H) < 2 ? 0 : 16384) + ((H) & 1) * 8192;   \
    size_t _ko = (size_t)(U) * 64 + (size_t)((H) & 1) * 128 * KP;                    \
    if ((H) < 2) { GLOAD(gA0 + _ko, _lb + dst0); GLOAD(gA1 + _ko, _lb + dst1); }     \
    else         { GLOAD(gB0 + _ko, _lb + dst0); GLOAD(gB1 + _ko, _lb + dst1); }     \
  } while (0)

// swizzled ds_read_b128 of one MFMA fragment (proven 0-conflict pattern)
#define RD_A(mi, kk) (*reinterpret_cast<const bf16x8*>(bufA + (wr * 128 + (mi) * 16 + f) * 64 + (((kk) * 4 + q) ^ f7) * 8))
#define RD_B(ni, kk) (*reinterpret_cast<const bf16x8*>(bufB + (wc * 64 + (ni) * 16 + f) * 64 + (((kk) * 4 + q) ^ f7) * 8))

#define RDA4(MOFF) do {                                                              \
    _Pragma("unroll") for (int _i = 0; _i < 4; ++_i) {                               \
      a_[_i][0] = RD_A((MOFF) + _i, 0); a_[_i][1] = RD_A((MOFF) + _i, 1); }          \
  } while (0)
#define RDB2(NOFF) do {                                                              \
    _Pragma("unroll") for (int _i = 0; _i < 2; ++_i) {                               \
      b_[(NOFF) + _i][0] = RD_B((NOFF) + _i, 0); b_[(NOFF) + _i][1] = RD_B((NOFF) + _i, 1); } \
  } while (0)

// one C-quadrant (4 M-frags x 2 N-frags x K=64) = 16 MFMA, setprio-wrapped (T5)
#define QUAD(MOFF, NOFF) do {                                                        \
    __builtin_amdgcn_s_setprio(1);                                                   \
    _Pragma("unroll") for (int _m = 0; _m < 4; ++_m)                                 \
    _Pragma("unroll") for (int _n = 0; _n < 2; ++_n)                                 \
    _Pragma("unroll") for (int _k = 0; _k < 2; ++_k)                                 \
      acc[(MOFF) + _m][(NOFF) + _n] = __builtin_amdgcn_mfma_f32_16x16x32_bf16(       \
          a_[_m][_k], b_[(NOFF) + _n][_k], acc[(MOFF) + _m][(NOFF) + _n], 0, 0, 0);  \
    __builtin_amdgcn_s_setprio(0);                                                   \
  } while (0)

  f32x4 acc[8][4] = {};
  bf16x8 a_[4][2], b_[4][2];
  const u16 *bufA, *bufB;

  // prologue: tile0 fully (8 loads) + tile1 h0 (2 loads, in flight across fence)
  STGH(0, 0); STGH(0, 1); STGH(0, 2); STGH(0, 3);
  STGH(1, 0);
  asm volatile("s_waitcnt vmcnt(2)" ::: "memory");
  bar();

  // R2 staging schedule (fine interleave): ph1 h1, ph2 h2, ph3 h3, ph4 h0(next) + vmcnt(2)
  for (int t = 0; t < NT - 1; t += 2) {
    // ---------------- tile t (buf 0) ----------------
    bufA = lds; bufB = lds + 16384;
    RDA4(0); RDB2(0);
    STGH(t + 1, 1);
    bar(); QUAD(0, 0); bar();

    RDB2(2);
    STGH(t + 1, 2);
    bar(); QUAD(0, 2); bar();

    RDA4(4);
    STGH(t + 1, 3);
    bar(); QUAD(4, 2); bar();

    STGH(t + 2, 0);
    asm volatile("s_waitcnt vmcnt(2)" ::: "memory");   // tile t+1 fully resident
    bar(); QUAD(4, 0); bar();

    // ---------------- tile t+1 (buf 1) ----------------
    bufA = lds + 32768; bufB = bufA + 16384;
    RDA4(0); RDB2(0);
    STGH(t + 2, 1);
    bar(); QUAD(0, 0); bar();

    RDB2(2);
    STGH(t + 2, 2);
    bar(); QUAD(0, 2); bar();

    RDA4(4);
    STGH(t + 2, 3);
    bar(); QUAD(4, 2); bar();

    if (t + 3 < NT) {
      STGH(t + 3, 0);
      asm volatile("s_waitcnt vmcnt(2)" ::: "memory"); // tile t+2 fully resident
    } else {
      asm volatile("s_waitcnt vmcnt(0)" ::: "memory"); // last: drain everything
    }
    bar(); QUAD(4, 0); bar();
  }

  // ---------------- tail tile NT-1 = 16 (buf 0), fully resident ----------------
  bufA = lds; bufB = lds + 16384;
  RDA4(0); RDB2(0); QUAD(0, 0);
  RDB2(2);          QUAD(0, 2);
  RDA4(4);          QUAD(4, 2); QUAD(4, 0);

  // epilogue: C/D layout col = lane&15, row = (lane>>4)*4 + j
  const int r0 = brow + wr * 128 + q * 4;
  const int c0 = bcol + wc * 64 + f;
#pragma unroll
  for (int mi = 0; mi < 8; ++mi)
#pragma unroll
    for (int ni = 0; ni < 4; ++ni) {
#pragma unroll
      for (int j = 0; j < 4; ++j)
        out[(size_t)(r0 + mi * 16 + j) * NDIM + (c0 + ni * 16)] = acc[mi][ni][j];
    }
}

// ---------------- fallback (ws too small): correct fp32 path on raw features ----------------
__global__ void fallback_kernel(const float* __restrict__ z, const float* __restrict__ W,
                                const float* __restrict__ bias, float* __restrict__ out) {
  __shared__ float feat[4369];
  const int row = blockIdx.x;
  const int tid = threadIdx.x;
  for (int t = tid; t < 4369; t += 256) {
    float v;
    if (t == 0) v = 1.0f;
    else if (t < 17) v = z[row * 16 + t - 1];
    else if (t < 273) { int u = t - 17; v = z[row * 16 + (u >> 4)] * z[row * 16 + (u & 15)]; }
    else { int u = t - 273; v = z[row * 16 + ((u >> 8) & 15)] * (z[row * 16 + ((u >> 4) & 15)] * z[row * 16 + (u & 15)]); }
    feat[t] = v;
  }
  __syncthreads();
  float acc[16];
#pragma unroll
  for (int j = 0; j < 16; ++j) acc[j] = bias[tid + 256 * j];
  for (int t = 0; t < 4369; ++t) {
    const float fv = feat[t];
    const float* wrow = W + (size_t)t * NDIM;
#pragma unroll
    for (int j = 0; j < 16; ++j) acc[j] = fmaf(fv, wrow[tid + 256 * j], acc[j]);
  }
  float* orow = out + (size_t)row * NDIM;
#pragma unroll
  for (int j = 0; j < 16; ++j) orow[tid + 256 * j] = acc[j];
}

extern "C" void kernel_launch(void* const* d_in, const int* in_sizes, int n_in,
                              void* d_out, int out_size, void* d_ws, size_t ws_size,
                              hipStream_t stream) {
  const float* z = (const float*)d_in[0];
  const float* W = (const float*)d_in[1];
  const float* b = (const float*)d_in[2];
  float* out = (float*)d_out;

  const size_t xb_elems  = (size_t)MROWS * KP;
  const size_t wbt_elems = (size_t)NDIM * KP;
  const size_t need = (xb_elems + wbt_elems) * sizeof(u16) + KP * sizeof(int);

  if (ws_size >= need) {
    u16* xb   = (u16*)d_ws;
    u16* wbt  = xb + xb_elems;
    int* table = (int*)(wbt + wbt_elems);
    map_kernel<<<(KP + 255) / 256, 256, 0, stream>>>(table);
    feat_kernel<<<MROWS, 256, 0, stream>>>(z, table, xb);
    wfold_kernel<<<dim3(KP / 64, NDIM / 64), 256, 0, stream>>>(W, b, table, wbt);
    gemm_kernel<<<(MROWS / 256) * (NDIM / 256), 512, 0, stream>>>(xb, wbt, out);
  } else {
    fallback_kernel<<<MROWS, 256, 0, stream>>>(z, W, b, out);
  }
}

// Round 8
// 107.025 us; speedup vs baseline: 3.0548x; 1.6921x over previous
//
#include <hip/hip_runtime.h>
#include <hip/hip_bf16.h>

#define NDIM  4096
#define MROWS 8192
// folded feature space: 1 + 16 + 136 + 816 = 969 distinct multiset products, padded to 17*64
#define PREAL 969
#define KP    1088   // 17 * 64
#define NT    17
#define NWFOLD 1088  // wfold blocks: 17 x 64

typedef unsigned short u16;
typedef __attribute__((ext_vector_type(8))) __bf16 bf16x8;
typedef __attribute__((ext_vector_type(8))) u16 u16x8;
typedef __attribute__((ext_vector_type(4))) float f32x4;

__device__ __forceinline__ u16 bf16rne(float f) {
  unsigned int u = __builtin_bit_cast(unsigned int, f);
  u += 0x7fffu + ((u >> 16) & 1u);
  return (u16)(u >> 16);
}

// -------- compile-time multiset table: TBL.v[p] = (i<<10)|(j<<5)|k, idx 16 = "1"; -1 = pad --------
struct Tbl { int v[KP]; };
constexpr Tbl make_table() {
  Tbl t{};
  for (int p = 0; p < KP; ++p) t.v[p] = -1;
  int p = 0;
  t.v[p++] = (16 << 10) | (16 << 5) | 16;                      // constant term
  for (int i = 0; i < 16; ++i) t.v[p++] = (i << 10) | (16 << 5) | 16;
  for (int i = 0; i < 16; ++i)
    for (int j = i; j < 16; ++j) t.v[p++] = (i << 10) | (j << 5) | 16;
  for (int i = 0; i < 16; ++i)
    for (int j = i; j < 16; ++j)
      for (int k = j; k < 16; ++k) t.v[p++] = (i << 10) | (j << 5) | k;
  return t;
}
__device__ constexpr Tbl TBL = make_table();

// -------- merged prep: blocks [0,NWFOLD) fold W; blocks [NWFOLD, NWFOLD+MROWS) build features --------
__global__ void prep_kernel(const float* __restrict__ z, const float* __restrict__ W,
                            const float* __restrict__ bias,
                            u16* __restrict__ xb, u16* __restrict__ wfbt) {
  __shared__ float tile[64][65];   // wfold transpose staging (65: 2-way conflicts = free)
  __shared__ float zs[17];
  const int bx = blockIdx.x;
  const int tid = threadIdx.x;

  if (bx < NWFOLD) {
    // ---- wfold: wfbt[d][p] = bf16( sum_{t in perms(p)} W[t][d] + (p==0 ? b[d] : 0) ) ----
    const int p0 = (bx % 17) * 64;
    const int d0 = (bx / 17) * 64;
    const int d4 = (tid & 15) * 4;   // float4 column offset
    const int rb = tid >> 4;         // 0..15
    const int dd = d0 + d4;
#pragma unroll
    for (int pp = 0; pp < 4; ++pp) {
      const int r = pp * 16 + rb;
      const int p = p0 + r;
      const int enc = TBL.v[p];
      f32x4 v = {0.f, 0.f, 0.f, 0.f};
      if (enc >= 0) {
        const int i = enc >> 10, j = (enc >> 5) & 31, k = enc & 31;
        if (k == 16) {
          if (j == 16) {
            if (i == 16) {
              v = *reinterpret_cast<const f32x4*>(W + dd);
              f32x4 bb = *reinterpret_cast<const f32x4*>(bias + dd);
              v.x += bb.x; v.y += bb.y; v.z += bb.z; v.w += bb.w;
            } else {
              v = *reinterpret_cast<const f32x4*>(W + (size_t)(1 + i) * NDIM + dd);
            }
          } else {  // degree 2, i<=j
            v = *reinterpret_cast<const f32x4*>(W + (size_t)(17 + i * 16 + j) * NDIM + dd);
            if (i != j) {
              f32x4 w2 = *reinterpret_cast<const f32x4*>(W + (size_t)(17 + j * 16 + i) * NDIM + dd);
              v.x += w2.x; v.y += w2.y; v.z += w2.z; v.w += w2.w;
            }
          }
        } else {    // degree 3, i<=j<=k
          int rows[6];
          int nr = 0;
          rows[nr++] = 273 + i * 256 + j * 16 + k;
          if (i == j && j == k) {
          } else if (i == j) {
            rows[nr++] = 273 + i * 256 + k * 16 + i;
            rows[nr++] = 273 + k * 256 + i * 16 + i;
          } else if (j == k) {
            rows[nr++] = 273 + j * 256 + i * 16 + j;
            rows[nr++] = 273 + j * 256 + j * 16 + i;
          } else {
            rows[nr++] = 273 + i * 256 + k * 16 + j;
            rows[nr++] = 273 + j * 256 + i * 16 + k;
            rows[nr++] = 273 + j * 256 + k * 16 + i;
            rows[nr++] = 273 + k * 256 + i * 16 + j;
            rows[nr++] = 273 + k * 256 + j * 16 + i;
          }
          v = *reinterpret_cast<const f32x4*>(W + (size_t)rows[0] * NDIM + dd);
          for (int s = 1; s < nr; ++s) {
            f32x4 w2 = *reinterpret_cast<const f32x4*>(W + (size_t)rows[s] * NDIM + dd);
            v.x += w2.x; v.y += w2.y; v.z += w2.z; v.w += w2.w;
          }
        }
      }
#pragma unroll
      for (int jj = 0; jj < 4; ++jj) tile[r][d4 + jj] = v[jj];
    }
    __syncthreads();
#pragma unroll
    for (int round = 0; round < 2; ++round) {
      const int v = round * 256 + tid;
      const int d = v >> 3;   // 0..63
      const int tg = v & 7;   // 0..7
      u16x8 pack;
#pragma unroll
      for (int e = 0; e < 8; ++e) pack[e] = bf16rne(tile[tg * 8 + e][d]);
      *reinterpret_cast<u16x8*>(wfbt + (size_t)(d0 + d) * KP + p0 + tg * 8) = pack;
    }
  } else {
    // ---- feat: xb[row][p] = bf16( z_i * z_j * z_k ) ----
    const int row = bx - NWFOLD;
    if (tid < 16) zs[tid] = z[row * 16 + tid];
    if (tid == 16) zs[16] = 1.0f;
    __syncthreads();
    u16* xrow = xb + (size_t)row * KP;
    for (int g = tid; g < KP / 8; g += 256) {
      u16x8 pack;
#pragma unroll
      for (int e = 0; e < 8; ++e) {
        const int enc = TBL.v[g * 8 + e];
        float v = 0.0f;
        if (enc >= 0) v = zs[enc >> 10] * (zs[(enc >> 5) & 31] * zs[enc & 31]);
        pack[e] = bf16rne(v);
      }
      *reinterpret_cast<u16x8*>(xrow + g * 8) = pack;
    }
  }
}

// ---------------- 256x256 8-phase GEMM (R2 schedule + chunked XCD swizzle), K=1088 ----------------
#define GLOAD(gp, lp)                                                                     \
  __builtin_amdgcn_global_load_lds((const __attribute__((address_space(1))) unsigned int*)(gp), \
                                   (__attribute__((address_space(3))) unsigned int*)(lp), 16, 0, 0)

__device__ __forceinline__ void bar() {
  asm volatile("" ::: "memory");
  __builtin_amdgcn_s_barrier();
  asm volatile("" ::: "memory");
}

__global__ __launch_bounds__(512, 2) void gemm_kernel(const u16* __restrict__ xb,
                                                      const u16* __restrict__ wbt,
                                                      float* __restrict__ out) {
  __shared__ u16 lds[2 * 32768];  // 128 KiB: per buffer A[256][64] + B[256][64]

  // XCD swizzle, chunked 4Mx8N per concurrent 32-block round (nwg=512, 512%8==0)
  const int bid  = blockIdx.x;
  const int xcd  = bid & 7;
  const int idx  = bid >> 3;            // 0..63 within XCD
  const int mtl  = (idx >> 3) & 3;      // 4 M-tiles per XCD
  const int ntl  = (idx & 7) | ((idx >> 5) << 3);  // 8 N-tiles per round, 2 rounds
  const int brow = (xcd * 4 + mtl) * 256;
  const int bcol = ntl * 256;

  const int tid  = threadIdx.x;
  const int lane = tid & 63;
  const int wid  = tid >> 6;   // 0..7
  const int wr   = wid >> 2;   // 0..1
  const int wc   = wid & 3;    // 0..3
  const int f    = lane & 15;
  const int q    = lane >> 4;
  const int f7   = f & 7;

  // staging geometry: wave-instr (wid,j) covers half-tile rows wid*16+j*8 .. +8
  // LDS dest linear (base + lane*16); global source pre-swizzled: chunk = (lane&7) ^ (row&7)
  const int srow0 = wid * 16 + (lane >> 3);
  const int srow1 = srow0 + 8;
  const u16* gA0 = xb  + (size_t)(brow + srow0) * KP + ((lane & 7) ^ (srow0 & 7)) * 8;
  const u16* gA1 = xb  + (size_t)(brow + srow1) * KP + ((lane & 7) ^ (srow1 & 7)) * 8;
  const u16* gB0 = wbt + (size_t)(bcol + srow0) * KP + ((lane & 7) ^ (srow0 & 7)) * 8;
  const u16* gB1 = wbt + (size_t)(bcol + srow1) * KP + ((lane & 7) ^ (srow1 & 7)) * 8;
  const int dst0 = wid * 1024;        // u16 elems within half-region
  const int dst1 = dst0 + 512;

// stage half-tile H (0,1 = A halves; 2,3 = B halves) of K-tile U into buf (U&1)
#define STGH(U, H) do {                                                              \
    u16* _lb = lds + ((U) & 1) * 32768 + ((H) < 2 ? 0 : 16384) + ((H) & 1) * 8192;   \
    size_t _ko = (size_t)(U) * 64 + (size_t)((H) & 1) * 128 * KP;                    \
    if ((H) < 2) { GLOAD(gA0 + _ko, _lb + dst0); GLOAD(gA1 + _ko, _lb + dst1); }     \
    else         { GLOAD(gB0 + _ko, _lb + dst0); GLOAD(gB1 + _ko, _lb + dst1); }     \
  } while (0)

// swizzled ds_read_b128 of one MFMA fragment (proven 0-conflict pattern)
#define RD_A(mi, kk) (*reinterpret_cast<const bf16x8*>(bufA + (wr * 128 + (mi) * 16 + f) * 64 + (((kk) * 4 + q) ^ f7) * 8))
#define RD_B(ni, kk) (*reinterpret_cast<const bf16x8*>(bufB + (wc * 64 + (ni) * 16 + f) * 64 + (((kk) * 4 + q) ^ f7) * 8))

#define RDA4(MOFF) do {                                                              \
    _Pragma("unroll") for (int _i = 0; _i < 4; ++_i) {                               \
      a_[_i][0] = RD_A((MOFF) + _i, 0); a_[_i][1] = RD_A((MOFF) + _i, 1); }          \
  } while (0)
#define RDB2(NOFF) do {                                                              \
    _Pragma("unroll") for (int _i = 0; _i < 2; ++_i) {                               \
      b_[(NOFF) + _i][0] = RD_B((NOFF) + _i, 0); b_[(NOFF) + _i][1] = RD_B((NOFF) + _i, 1); } \
  } while (0)

// one C-quadrant (4 M-frags x 2 N-frags x K=64) = 16 MFMA, setprio-wrapped (T5)
#define QUAD(MOFF, NOFF) do {                                                        \
    __builtin_amdgcn_s_setprio(1);                                                   \
    _Pragma("unroll") for (int _m = 0; _m < 4; ++_m)                                 \
    _Pragma("unroll") for (int _n = 0; _n < 2; ++_n)                                 \
    _Pragma("unroll") for (int _k = 0; _k < 2; ++_k)                                 \
      acc[(MOFF) + _m][(NOFF) + _n] = __builtin_amdgcn_mfma_f32_16x16x32_bf16(       \
          a_[_m][_k], b_[(NOFF) + _n][_k], acc[(MOFF) + _m][(NOFF) + _n], 0, 0, 0);  \
    __builtin_amdgcn_s_setprio(0);                                                   \
  } while (0)

  f32x4 acc[8][4] = {};
  bf16x8 a_[4][2], b_[4][2];
  const u16 *bufA, *bufB;

  // prologue: tile0 fully (8 loads) + tile1 h0 (2 loads, in flight across fence)
  STGH(0, 0); STGH(0, 1); STGH(0, 2); STGH(0, 3);
  STGH(1, 0);
  asm volatile("s_waitcnt vmcnt(2)" ::: "memory");
  bar();

  // R2 staging schedule (fine interleave): ph1 h1, ph2 h2, ph3 h3, ph4 h0(next) + vmcnt(2)
  for (int t = 0; t < NT - 1; t += 2) {
    // ---------------- tile t (buf 0) ----------------
    bufA = lds; bufB = lds + 16384;
    RDA4(0); RDB2(0);
    STGH(t + 1, 1);
    bar(); QUAD(0, 0); bar();

    RDB2(2);
    STGH(t + 1, 2);
    bar(); QUAD(0, 2); bar();

    RDA4(4);
    STGH(t + 1, 3);
    bar(); QUAD(4, 2); bar();

    STGH(t + 2, 0);
    asm volatile("s_waitcnt vmcnt(2)" ::: "memory");   // tile t+1 fully resident
    bar(); QUAD(4, 0); bar();

    // ---------------- tile t+1 (buf 1) ----------------
    bufA = lds + 32768; bufB = bufA + 16384;
    RDA4(0); RDB2(0);
    STGH(t + 2, 1);
    bar(); QUAD(0, 0); bar();

    RDB2(2);
    STGH(t + 2, 2);
    bar(); QUAD(0, 2); bar();

    RDA4(4);
    STGH(t + 2, 3);
    bar(); QUAD(4, 2); bar();

    if (t + 3 < NT) {
      STGH(t + 3, 0);
      asm volatile("s_waitcnt vmcnt(2)" ::: "memory"); // tile t+2 fully resident
    } else {
      asm volatile("s_waitcnt vmcnt(0)" ::: "memory"); // last: drain everything
    }
    bar(); QUAD(4, 0); bar();
  }

  // ---------------- tail tile NT-1 = 16 (buf 0), fully resident ----------------
  bufA = lds; bufB = lds + 16384;
  RDA4(0); RDB2(0); QUAD(0, 0);
  RDB2(2);          QUAD(0, 2);
  RDA4(4);          QUAD(4, 2); QUAD(4, 0);

  // epilogue: C/D layout col = lane&15, row = (lane>>4)*4 + j
  const int r0 = brow + wr * 128 + q * 4;
  const int c0 = bcol + wc * 64 + f;
#pragma unroll
  for (int mi = 0; mi < 8; ++mi)
#pragma unroll
    for (int ni = 0; ni < 4; ++ni) {
#pragma unroll
      for (int j = 0; j < 4; ++j)
        out[(size_t)(r0 + mi * 16 + j) * NDIM + (c0 + ni * 16)] = acc[mi][ni][j];
    }
}

// ---------------- fallback (ws too small): correct fp32 path on raw features ----------------
__global__ void fallback_kernel(const float* __restrict__ z, const float* __restrict__ W,
                                const float* __restrict__ bias, float* __restrict__ out) {
  __shared__ float feat[4369];
  const int row = blockIdx.x;
  const int tid = threadIdx.x;
  for (int t = tid; t < 4369; t += 256) {
    float v;
    if (t == 0) v = 1.0f;
    else if (t < 17) v = z[row * 16 + t - 1];
    else if (t < 273) { int u = t - 17; v = z[row * 16 + (u >> 4)] * z[row * 16 + (u & 15)]; }
    else { int u = t - 273; v = z[row * 16 + ((u >> 8) & 15)] * (z[row * 16 + ((u >> 4) & 15)] * z[row * 16 + (u & 15)]); }
    feat[t] = v;
  }
  __syncthreads();
  float acc[16];
#pragma unroll
  for (int j = 0; j < 16; ++j) acc[j] = bias[tid + 256 * j];
  for (int t = 0; t < 4369; ++t) {
    const float fv = feat[t];
    const float* wrow = W + (size_t)t * NDIM;
#pragma unroll
    for (int j = 0; j < 16; ++j) acc[j] = fmaf(fv, wrow[tid + 256 * j], acc[j]);
  }
  float* orow = out + (size_t)row * NDIM;
#pragma unroll
  for (int j = 0; j < 16; ++j) orow[tid + 256 * j] = acc[j];
}

extern "C" void kernel_launch(void* const* d_in, const int* in_sizes, int n_in,
                              void* d_out, int out_size, void* d_ws, size_t ws_size,
                              hipStream_t stream) {
  const float* z = (const float*)d_in[0];
  const float* W = (const float*)d_in[1];
  const float* b = (const float*)d_in[2];
  float* out = (float*)d_out;

  const size_t xb_elems  = (size_t)MROWS * KP;
  const size_t wbt_elems = (size_t)NDIM * KP;
  const size_t need = (xb_elems + wbt_elems) * sizeof(u16);

  if (ws_size >= need) {
    u16* xb  = (u16*)d_ws;
    u16* wbt = xb + xb_elems;
    prep_kernel<<<NWFOLD + MROWS, 256, 0, stream>>>(z, W, b, xb, wbt);
    gemm_kernel<<<(MROWS / 256) * (NDIM / 256), 512, 0, stream>>>(xb, wbt, out);
  } else {
    fallback_kernel<<<MROWS, 256, 0, stream>>>(z, W, b, out);
  }
}

// Round 9
// 104.277 us; speedup vs baseline: 3.1353x; 1.0264x over previous
//
#include <hip/hip_runtime.h>
#include <hip/hip_bf16.h>

#define NDIM  4096
#define MROWS 8192
// folded feature space: 1 + 16 + 136 + 816 = 969 distinct multiset products, padded to 16*64
#define PREAL 969
#define KP    1024   // 16 * 64  (tile 16 of the old 1088 was all-pad -> dropped)
#define NT    16
#define NWFOLD 1024  // wfold blocks: 16 x 64

typedef unsigned short u16;
typedef __attribute__((ext_vector_type(8))) __bf16 bf16x8;
typedef __attribute__((ext_vector_type(8))) u16 u16x8;
typedef __attribute__((ext_vector_type(4))) float f32x4;

__device__ __forceinline__ u16 bf16rne(float f) {
  unsigned int u = __builtin_bit_cast(unsigned int, f);
  u += 0x7fffu + ((u >> 16) & 1u);
  return (u16)(u >> 16);
}

// -------- compile-time multiset table: TBL.v[p] = (i<<10)|(j<<5)|k, idx 16 = "1"; -1 = pad --------
struct Tbl { int v[KP]; };
constexpr Tbl make_table() {
  Tbl t{};
  for (int p = 0; p < KP; ++p) t.v[p] = -1;
  int p = 0;
  t.v[p++] = (16 << 10) | (16 << 5) | 16;                      // constant term
  for (int i = 0; i < 16; ++i) t.v[p++] = (i << 10) | (16 << 5) | 16;
  for (int i = 0; i < 16; ++i)
    for (int j = i; j < 16; ++j) t.v[p++] = (i << 10) | (j << 5) | 16;
  for (int i = 0; i < 16; ++i)
    for (int j = i; j < 16; ++j)
      for (int k = j; k < 16; ++k) t.v[p++] = (i << 10) | (j << 5) | k;
  return t;
}
__device__ constexpr Tbl TBL = make_table();

// -------- merged prep: blocks [0,NWFOLD) fold W; blocks [NWFOLD, NWFOLD+MROWS) build features --------
__global__ void prep_kernel(const float* __restrict__ z, const float* __restrict__ W,
                            const float* __restrict__ bias,
                            u16* __restrict__ xb, u16* __restrict__ wfbt) {
  __shared__ float tile[64][65];   // wfold transpose staging (65: 2-way conflicts = free)
  __shared__ float zs[17];
  const int bx = blockIdx.x;
  const int tid = threadIdx.x;

  if (bx < NWFOLD) {
    // ---- wfold: wfbt[d][p] = bf16( sum_{t in perms(p)} W[t][d] + (p==0 ? b[d] : 0) ) ----
    const int p0 = (bx & 15) * 64;
    const int d0 = (bx >> 4) * 64;
    const int d4 = (tid & 15) * 4;   // float4 column offset
    const int rb = tid >> 4;         // 0..15
    const int dd = d0 + d4;
#pragma unroll
    for (int pp = 0; pp < 4; ++pp) {
      const int r = pp * 16 + rb;
      const int p = p0 + r;
      const int enc = TBL.v[p];
      f32x4 v = {0.f, 0.f, 0.f, 0.f};
      if (enc >= 0) {
        const int i = enc >> 10, j = (enc >> 5) & 31, k = enc & 31;
        if (k == 16) {
          if (j == 16) {
            if (i == 16) {
              v = *reinterpret_cast<const f32x4*>(W + dd);
              f32x4 bb = *reinterpret_cast<const f32x4*>(bias + dd);
              v.x += bb.x; v.y += bb.y; v.z += bb.z; v.w += bb.w;
            } else {
              v = *reinterpret_cast<const f32x4*>(W + (size_t)(1 + i) * NDIM + dd);
            }
          } else {  // degree 2, i<=j
            v = *reinterpret_cast<const f32x4*>(W + (size_t)(17 + i * 16 + j) * NDIM + dd);
            if (i != j) {
              f32x4 w2 = *reinterpret_cast<const f32x4*>(W + (size_t)(17 + j * 16 + i) * NDIM + dd);
              v.x += w2.x; v.y += w2.y; v.z += w2.z; v.w += w2.w;
            }
          }
        } else {    // degree 3, i<=j<=k
          int rows[6];
          int nr = 0;
          rows[nr++] = 273 + i * 256 + j * 16 + k;
          if (i == j && j == k) {
          } else if (i == j) {
            rows[nr++] = 273 + i * 256 + k * 16 + i;
            rows[nr++] = 273 + k * 256 + i * 16 + i;
          } else if (j == k) {
            rows[nr++] = 273 + j * 256 + i * 16 + j;
            rows[nr++] = 273 + j * 256 + j * 16 + i;
          } else {
            rows[nr++] = 273 + i * 256 + k * 16 + j;
            rows[nr++] = 273 + j * 256 + i * 16 + k;
            rows[nr++] = 273 + j * 256 + k * 16 + i;
            rows[nr++] = 273 + k * 256 + i * 16 + j;
            rows[nr++] = 273 + k * 256 + j * 16 + i;
          }
          v = *reinterpret_cast<const f32x4*>(W + (size_t)rows[0] * NDIM + dd);
          for (int s = 1; s < nr; ++s) {
            f32x4 w2 = *reinterpret_cast<const f32x4*>(W + (size_t)rows[s] * NDIM + dd);
            v.x += w2.x; v.y += w2.y; v.z += w2.z; v.w += w2.w;
          }
        }
      }
#pragma unroll
      for (int jj = 0; jj < 4; ++jj) tile[r][d4 + jj] = v[jj];
    }
    __syncthreads();
#pragma unroll
    for (int round = 0; round < 2; ++round) {
      const int v = round * 256 + tid;
      const int d = v >> 3;   // 0..63
      const int tg = v & 7;   // 0..7
      u16x8 pack;
#pragma unroll
      for (int e = 0; e < 8; ++e) pack[e] = bf16rne(tile[tg * 8 + e][d]);
      *reinterpret_cast<u16x8*>(wfbt + (size_t)(d0 + d) * KP + p0 + tg * 8) = pack;
    }
  } else {
    // ---- feat: xb[row][p] = bf16( z_i * z_j * z_k ) ----
    const int row = bx - NWFOLD;
    if (tid < 16) zs[tid] = z[row * 16 + tid];
    if (tid == 16) zs[16] = 1.0f;
    __syncthreads();
    u16* xrow = xb + (size_t)row * KP;
    for (int g = tid; g < KP / 8; g += 256) {
      u16x8 pack;
#pragma unroll
      for (int e = 0; e < 8; ++e) {
        const int enc = TBL.v[g * 8 + e];
        float v = 0.0f;
        if (enc >= 0) v = zs[enc >> 10] * (zs[(enc >> 5) & 31] * zs[enc & 31]);
        pack[e] = bf16rne(v);
      }
      *reinterpret_cast<u16x8*>(xrow + g * 8) = pack;
    }
  }
}

// ------- 256x256 8-phase GEMM, phase-matched quarters + staggered counted vmcnt, K=1024 -------
#define GLOAD(gp, lp)                                                                     \
  __builtin_amdgcn_global_load_lds((const __attribute__((address_space(1))) unsigned int*)(gp), \
                                   (__attribute__((address_space(3))) unsigned int*)(lp), 16, 0, 0)

__device__ __forceinline__ void bar() {
  asm volatile("" ::: "memory");
  __builtin_amdgcn_s_barrier();
  asm volatile("" ::: "memory");
}

#define VM4 asm volatile("s_waitcnt vmcnt(4)" ::: "memory")

__global__ __launch_bounds__(512, 2) void gemm_kernel(const u16* __restrict__ xb,
                                                      const u16* __restrict__ wbt,
                                                      float* __restrict__ out) {
  __shared__ u16 lds[2 * 32768];  // 128 KiB: per buffer A[256][64] + B[256][64]

  // XCD swizzle, chunked 4Mx8N per concurrent 32-block round (nwg=512, 512%8==0)
  const int bid  = blockIdx.x;
  const int xcd  = bid & 7;
  const int idx  = bid >> 3;            // 0..63 within XCD
  const int mtl  = (idx >> 3) & 3;      // 4 M-tiles per XCD
  const int ntl  = (idx & 7) | ((idx >> 5) << 3);  // 8 N-tiles per round, 2 rounds
  const int brow = (xcd * 4 + mtl) * 256;
  const int bcol = ntl * 256;

  const int tid  = threadIdx.x;
  const int lane = tid & 63;
  const int wid  = tid >> 6;   // 0..7
  const int wr   = wid >> 2;   // 0..1
  const int wc   = wid & 3;    // 0..3
  const int f    = lane & 15;
  const int q    = lane >> 4;
  const int f7   = f & 7;

  // ---- staging geometry: quarters matched to phase read-sets ----
  // Ah0 = A rows {0-63, 128-191}   (read ph1: RDA4(0) for both wr)
  // Ah1 = A rows {64-127, 192-255} (read ph3)
  // Bh0 = B rows {wc*64+0..31}     (read ph1)    Bh1 = {wc*64+32..63} (read ph2)
  const int lr = lane >> 3;                         // 0..7
  const int swzc = ((lane & 7) ^ lr) * 8;           // pre-swizzled source chunk (u16)
  const u16* gA = xb  + (size_t)(brow + lr) * KP + swzc;
  const u16* gB = wbt + (size_t)(bcol + lr) * KP + swzc;
  const int aB0 = (wid >> 2) * 128 + (wid & 3) * 16;  // Ah0 16-row group base; Ah1 = +64
  const int bB0 = (wid >> 1) * 64 + (wid & 1) * 16;   // Bh0 16-row group base; Bh1 = +32

// stage 16 rows starting at rb of K-tile U from gptr into LDS region (linear dest)
#define STGQ(gptr, region, rb, U) do {                                               \
    GLOAD((gptr) + (size_t)(rb) * KP + (U) * 64, (region) + (rb) * 64);              \
    GLOAD((gptr) + (size_t)((rb) + 8) * KP + (U) * 64, (region) + ((rb) + 8) * 64);  \
  } while (0)

// swizzled ds_read_b128 of one MFMA fragment (proven 0-conflict pattern)
#define RD_A(mi, kk) (*reinterpret_cast<const bf16x8*>(bufA + (wr * 128 + (mi) * 16 + f) * 64 + (((kk) * 4 + q) ^ f7) * 8))
#define RD_B(ni, kk) (*reinterpret_cast<const bf16x8*>(bufB + (wc * 64 + (ni) * 16 + f) * 64 + (((kk) * 4 + q) ^ f7) * 8))

#define RDA4(MOFF) do {                                                              \
    _Pragma("unroll") for (int _i = 0; _i < 4; ++_i) {                               \
      a_[_i][0] = RD_A((MOFF) + _i, 0); a_[_i][1] = RD_A((MOFF) + _i, 1); }          \
  } while (0)
#define RDB2(NOFF) do {                                                              \
    _Pragma("unroll") for (int _i = 0; _i < 2; ++_i) {                               \
      b_[(NOFF) + _i][0] = RD_B((NOFF) + _i, 0); b_[(NOFF) + _i][1] = RD_B((NOFF) + _i, 1); } \
  } while (0)

// one C-quadrant (4 M-frags x 2 N-frags x K=64) = 16 MFMA, setprio-wrapped (T5)
#define QUAD(MOFF, NOFF) do {                                                        \
    __builtin_amdgcn_s_setprio(1);                                                   \
    _Pragma("unroll") for (int _m = 0; _m < 4; ++_m)                                 \
    _Pragma("unroll") for (int _n = 0; _n < 2; ++_n)                                 \
    _Pragma("unroll") for (int _k = 0; _k < 2; ++_k)                                 \
      acc[(MOFF) + _m][(NOFF) + _n] = __builtin_amdgcn_mfma_f32_16x16x32_bf16(       \
          a_[_m][_k], b_[(NOFF) + _n][_k], acc[(MOFF) + _m][(NOFF) + _n], 0, 0, 0);  \
    __builtin_amdgcn_s_setprio(0);                                                   \
  } while (0)

// one tile body: reads (cA,cB), stages K-tile U into (nA,nB)
// fences: vmcnt(4) after ph1/ph2/ph4 QUADs -> every staged quarter gets >=2 phases slack
#define TILE_BODY(cA, cB, nA, nB, U) do {                                            \
    bufA = (cA); bufB = (cB);                                                        \
    RDA4(0); RDB2(0); STGQ(gA, (nA), aB0, (U));                                      \
    bar(); QUAD(0, 0); VM4; bar();                                                   \
    RDB2(2);          STGQ(gB, (nB), bB0, (U));                                      \
    bar(); QUAD(0, 2); VM4; bar();                                                   \
    RDA4(4);          STGQ(gB, (nB), bB0 + 32, (U));                                 \
    bar(); QUAD(4, 2); bar();                                                        \
                      STGQ(gA, (nA), aB0 + 64, (U));                                 \
    bar(); QUAD(4, 0); VM4; bar();                                                   \
  } while (0)

  f32x4 acc[8][4] = {};
  bf16x8 a_[4][2], b_[4][2];
  const u16 *bufA, *bufB;

  u16* b0A = lds;            u16* b0B = lds + 16384;
  u16* b1A = lds + 32768;    u16* b1B = b1A + 16384;

  // prologue: stage tile0's 4 quarters in read order; vmcnt(4) -> Ah0,Bh0 resident
  STGQ(gA, b0A, aB0, 0); STGQ(gB, b0B, bB0, 0);
  STGQ(gB, b0B, bB0 + 32, 0); STGQ(gA, b0A, aB0 + 64, 0);
  VM4; bar();

  for (int t = 0; t < NT; t += 2) {
    const int u2 = (t + 2 < NT) ? (t + 2) : 0;        // dummy re-stage of tile0 keeps counts uniform
    TILE_BODY(b0A, b0B, b1A, b1B, t + 1);             // tile t   (even): reads buf0, stages t+1
    TILE_BODY(b1A, b1B, b0A, b0B, u2);                // tile t+1 (odd):  reads buf1, stages t+2/dummy
  }
  asm volatile("s_waitcnt vmcnt(0)" ::: "memory");    // drain dangling dummy stages

  // epilogue: C/D layout col = lane&15, row = (lane>>4)*4 + j
  const int r0 = brow + wr * 128 + q * 4;
  const int c0 = bcol + wc * 64 + f;
#pragma unroll
  for (int mi = 0; mi < 8; ++mi)
#pragma unroll
    for (int ni = 0; ni < 4; ++ni) {
#pragma unroll
      for (int j = 0; j < 4; ++j)
        out[(size_t)(r0 + mi * 16 + j) * NDIM + (c0 + ni * 16)] = acc[mi][ni][j];
    }
}

// ---------------- fallback (ws too small): correct fp32 path on raw features ----------------
__global__ void fallback_kernel(const float* __restrict__ z, const float* __restrict__ W,
                                const float* __restrict__ bias, float* __restrict__ out) {
  __shared__ float feat[4369];
  const int row = blockIdx.x;
  const int tid = threadIdx.x;
  for (int t = tid; t < 4369; t += 256) {
    float v;
    if (t == 0) v = 1.0f;
    else if (t < 17) v = z[row * 16 + t - 1];
    else if (t < 273) { int u = t - 17; v = z[row * 16 + (u >> 4)] * z[row * 16 + (u & 15)]; }
    else { int u = t - 273; v = z[row * 16 + ((u >> 8) & 15)] * (z[row * 16 + ((u >> 4) & 15)] * z[row * 16 + (u & 15)]); }
    feat[t] = v;
  }
  __syncthreads();
  float acc[16];
#pragma unroll
  for (int j = 0; j < 16; ++j) acc[j] = bias[tid + 256 * j];
  for (int t = 0; t < 4369; ++t) {
    const float fv = feat[t];
    const float* wrow = W + (size_t)t * NDIM;
#pragma unroll
    for (int j = 0; j < 16; ++j) acc[j] = fmaf(fv, wrow[tid + 256 * j], acc[j]);
  }
  float* orow = out + (size_t)row * NDIM;
#pragma unroll
  for (int j = 0; j < 16; ++j) orow[tid + 256 * j] = acc[j];
}

extern "C" void kernel_launch(void* const* d_in, const int* in_sizes, int n_in,
                              void* d_out, int out_size, void* d_ws, size_t ws_size,
                              hipStream_t stream) {
  const float* z = (const float*)d_in[0];
  const float* W = (const float*)d_in[1];
  const float* b = (const float*)d_in[2];
  float* out = (float*)d_out;

  const size_t xb_elems  = (size_t)MROWS * KP;
  const size_t wbt_elems = (size_t)NDIM * KP;
  const size_t need = (xb_elems + wbt_elems) * sizeof(u16);

  if (ws_size >= need) {
    u16* xb  = (u16*)d_ws;
    u16* wbt = xb + xb_elems;
    prep_kernel<<<NWFOLD + MROWS, 256, 0, stream>>>(z, W, b, xb, wbt);
    gemm_kernel<<<(MROWS / 256) * (NDIM / 256), 512, 0, stream>>>(xb, wbt, out);
  } else {
    fallback_kernel<<<MROWS, 256, 0, stream>>>(z, W, b, out);
  }
}